// Round 1
// baseline (59.633 us; speedup 1.0000x reference)
//
#include <hip/hip_runtime.h>

// RPQWeight gather:
//   indices:   (H=32, C=16384) int32, values in [0, 256)
//   codebooks: (H=32, NC=256, D=128) float32
//   out:       (C=16384, H*D=4096) float32
//   out[c, h*D + d] = codebooks[h, indices[h,c], d]
//
// Memory-bound: 256 MiB output write dominates. Output-centric float4
// mapping gives perfectly coalesced 16B/lane stores; codebooks (4 MiB)
// live in L2/L3 so gather reads are cheap.

#define RPQ_H  32
#define RPQ_C  16384
#define RPQ_D  128
#define RPQ_NC 256

__global__ void rpq_gather_kernel(const int* __restrict__ indices,
                                  const float* __restrict__ codebooks,
                                  float* __restrict__ out) {
    const float4* __restrict__ cb = reinterpret_cast<const float4*>(codebooks);
    float4* __restrict__ o = reinterpret_cast<float4*>(out);

    // total float4 elements in output: C * (H*D/4) = 16384 * 1024 = 16,777,216
    const unsigned total = (unsigned)RPQ_C * (RPQ_H * RPQ_D / 4);

    for (unsigned v = blockIdx.x * blockDim.x + threadIdx.x; v < total;
         v += gridDim.x * blockDim.x) {
        const unsigned c   = v >> 10;        // 1024 float4 per output row
        const unsigned rem = v & 1023u;
        const unsigned h   = rem >> 5;       // 32 float4 per codebook slice
        const unsigned d4  = rem & 31u;

        const int idx = indices[h * RPQ_C + c];
        // codebooks[h, idx, d4*4 .. d4*4+3]
        o[v] = cb[((h << 8) + (unsigned)idx) * 32u + d4];
    }
}

extern "C" void kernel_launch(void* const* d_in, const int* in_sizes, int n_in,
                              void* d_out, int out_size, void* d_ws, size_t ws_size,
                              hipStream_t stream) {
    const int*   indices   = (const int*)d_in[0];
    const float* codebooks = (const float*)d_in[1];
    float*       out       = (float*)d_out;

    const int block = 256;
    const int grid  = 2048;  // grid-stride; ~8 blocks/CU across 256 CUs
    rpq_gather_kernel<<<grid, block, 0, stream>>>(indices, codebooks, out);
}